// Round 8
// baseline (416.438 us; speedup 1.0000x reference)
//
#include <hip/hip_runtime.h>

#define S_LEN 2048
#define DINNER 512
#define NCHUNK 64
#define CLEN 32

typedef unsigned short u16;
typedef short bf16x8 __attribute__((ext_vector_type(8)));
typedef unsigned short u16x8 __attribute__((ext_vector_type(8)));  // 16 bytes
typedef unsigned short u16x4 __attribute__((ext_vector_type(4)));  // 8 bytes
typedef float f32x4 __attribute__((ext_vector_type(4)));

__device__ __forceinline__ float bf2f(u16 u) {
  unsigned int x = ((unsigned int)u) << 16;
  float f; __builtin_memcpy(&f, &x, 4); return f;
}
__device__ __forceinline__ u16 f2bf(float f) {
  unsigned int x; __builtin_memcpy(&x, &f, 4);
  return (u16)((x + 0x7FFFu + ((x >> 16) & 1u)) >> 16);
}
__device__ __forceinline__ float ldw(const void* p, size_t i, int isbf) {
  return isbf ? bf2f(((const u16*)p)[i]) : ((const float*)p)[i];
}
__device__ __forceinline__ float siluf(float x) { return x / (1.f + __expf(-x)); }
__device__ __forceinline__ float softplusf(float x) {
  if (x > 20.f) return x;
  return log1pf(__expf(x));
}

// Direct global->LDS DMA, 16B per lane. LDS dest = wave-uniform base + lane*16.
// Layout correctness proven in R2 (passed, absmax identical); this round fixes
// only the schedule (issue-early, drain at end-of-step barrier).
typedef __attribute__((address_space(1))) const void gvoid_t;
typedef __attribute__((address_space(3))) void lvoid_t;
__device__ __forceinline__ void glds16(const u16* g, u16* l) {
  __builtin_amdgcn_global_load_lds((gvoid_t*)g, (lvoid_t*)l, 16, 0, 0);
}

// ---------------- fused prologue: self-detect + apack + wpack + wpack_cmb ----------
// Each block detects input dtype itself (256 cached loads); block 0 publishes
// flagp for downstream kernels.
// Block ranges: [0,128) apack; [128,640) wpack in_w; [640,896) wpack out_w;
// [896,960) wpack merge_w; [960,1536) wpack_cmb.
// Packed W[K][N]: chunk c = nblk16*(K/32) + kblk32, 512 bf16 per chunk;
// inside: q*128 + (n&15)*8 + (k&7).
__global__ __launch_bounds__(256) void prep_kernel(
    const void* __restrict__ xinp,
    const void* __restrict__ A_log,
    const void* __restrict__ in_w, const void* __restrict__ out_w,
    const void* __restrict__ merge_w,
    const void* __restrict__ xdw, const void* __restrict__ dtpw,
    const void* __restrict__ xBw, const void* __restrict__ xCw,
    int* __restrict__ flagp,
    float* __restrict__ Acp, u16* __restrict__ Wp_in, u16* __restrict__ Wp_out,
    u16* __restrict__ Wp_mg, u16* __restrict__ Wp_cmb)
{
  int b = blockIdx.x;
  int tid = threadIdx.x;
  __shared__ int cnt_s;
  if (tid == 0) cnt_s = 0;
  __syncthreads();
  {
    u16 u = ((const u16*)xinp)[2 * tid];
    int e = (u >> 7) & 0xFF;
    if (e >= 0x60 && e <= 0x8F) atomicAdd(&cnt_s, 1);
  }
  __syncthreads();
  const int isbf = (cnt_s > 128) ? 1 : 0;
  if (b == 0 && tid == 0) *flagp = isbf;

  __shared__ float smem[32 * 163];  // tile[32][65] | xd[32][33] | wt[32][65]
  float* tile = smem;               // [k][n] -> tile[k*65+n]

  if (b < 128) {  // ---- apack: Acp = -exp(A_log), 32768 elems ----
    int idx = b * 256 + tid;
    Acp[idx] = -__expf(ldw(A_log, (size_t)idx, isbf));
    return;
  }
  b -= 128;

  if (b < 512 + 256 + 64) {  // ---- generic wpack ----
    const void* src; u16* dst; int K, N, nb64, kb, mat;
    if (b < 512)      { src = in_w;    dst = Wp_in;  K = 256; N = 1024;
                        nb64 = b % 16; kb = (b / 16) % 8; mat = b / 128; }
    else if (b < 768) { int c = b - 512; src = out_w; dst = Wp_out; K = 512; N = 256;
                        nb64 = c % 4; kb = (c / 4) % 16; mat = c / 64; }
    else              { int c = b - 768; src = merge_w; dst = Wp_mg; K = 512; N = 256;
                        nb64 = c % 4; kb = (c / 4) % 16; mat = 0; }
    size_t so = (size_t)mat * K * N;
    int kk = tid >> 3, nseg = (tid & 7) * 8;
#pragma unroll
    for (int j = 0; j < 8; ++j)
      tile[kk * 65 + nseg + j] =
          ldw(src, so + (size_t)(kb * 32 + kk) * N + nb64 * 64 + nseg + j, isbf);
    __syncthreads();
    int cc = tid >> 6, i0 = (tid & 63) * 8;
    int q = i0 >> 7, nn = (i0 >> 3) & 15;
    u16 outv[8];
#pragma unroll
    for (int j = 0; j < 8; ++j) outv[j] = f2bf(tile[(q * 8 + j) * 65 + cc * 16 + nn]);
    size_t doff = (size_t)mat * K * N + ((size_t)(nb64 * 4 + cc) * (K >> 5) + kb) * 512 + i0;
    *(u16x8*)(dst + doff) = *(const u16x8*)outv;
    return;
  }
  b -= 832;

  // ---- wpack_cmb: [512 x 576] = [ xd_w@dtp_w (512) | xB_w (16) | xC_w (16) | 0 ] ----
  {
    int nb64 = b % 9, kb = (b / 9) % 16, mat = b / 144;
    float* xd = smem + 32 * 65;       // [k][j] -> xd[k*33+j]
    float* wt = smem + 32 * 98;       // [j][n] -> wt[j*65+n]
    if (nb64 < 8) {
      {
        int k = tid >> 3, j0 = (tid & 7) * 4;
#pragma unroll
        for (int j = 0; j < 4; ++j)
          xd[k * 33 + j0 + j] =
              ldw(xdw, (size_t)mat * 16384 + (size_t)(kb * 32 + k) * 32 + j0 + j, isbf);
        int jj = tid >> 3, n0l = (tid & 7) * 8;
#pragma unroll
        for (int n = 0; n < 8; ++n)
          wt[jj * 65 + n0l + n] =
              ldw(dtpw, (size_t)mat * 16384 + (size_t)jj * 512 + nb64 * 64 + n0l + n, isbf);
      }
      __syncthreads();
      for (int l = tid; l < 2048; l += 256) {
        int k = l >> 6, n = l & 63;
        float a = 0.f;
#pragma unroll
        for (int j = 0; j < 32; ++j) a += xd[k * 33 + j] * wt[j * 65 + n];
        tile[k * 65 + n] = a;
      }
    } else {
      for (int l = tid; l < 2048; l += 256) {
        int k = l >> 6, n = l & 63;
        int kg = kb * 32 + k;
        float v = 0.f;
        if (n < 16)      v = ldw(xBw, (size_t)mat * 8192 + (size_t)kg * 16 + n, isbf);
        else if (n < 32) v = ldw(xCw, (size_t)mat * 8192 + (size_t)kg * 16 + (n - 16), isbf);
        tile[k * 65 + n] = v;
      }
    }
    __syncthreads();
    int cc = tid >> 6, i0 = (tid & 63) * 8;
    int q = i0 >> 7, nn = (i0 >> 3) & 15;
    u16 outv[8];
#pragma unroll
    for (int j = 0; j < 8; ++j) outv[j] = f2bf(tile[(q * 8 + j) * 65 + cc * 16 + nn]);
    size_t doff = (size_t)mat * 294912 + ((size_t)(nb64 * 4 + cc) * 16 + kb) * 512 + i0;
    *(u16x8*)(Wp_cmb + doff) = *(const u16x8*)outv;
  }
}

// ---------------- LayerNorm: wave-per-row, no LDS/barriers, x4 vectorized --------
__global__ __launch_bounds__(256) void ln_kernel(
    const void* __restrict__ x, const u16* __restrict__ obA, int it,
    const void* __restrict__ g, const void* __restrict__ bta,
    const int* __restrict__ pf, u16* __restrict__ xnb)
{
  const int isbf = *pf;
  int tid = threadIdx.x;
  int w = tid >> 6, lane = tid & 63;
  int r = blockIdx.x * 4 + w;
  int chain = r >> 12, rr = r & 4095;
  int i = chain * 2 + it;
  size_t wo = (size_t)i * 256;
  int e0 = lane * 4;
  float v[4];
  if (it == 0) {
    int b = rr >> 11, s = rr & 2047;
    int sr = chain ? (b * S_LEN + (S_LEN - 1 - s)) : rr;
    if (isbf) {
      u16x4 u = *(const u16x4*)((const u16*)x + (size_t)sr * 256 + e0);
#pragma unroll
      for (int j = 0; j < 4; ++j) v[j] = bf2f(u[j]);
    } else {
      f32x4 u = *(const f32x4*)((const float*)x + (size_t)sr * 256 + e0);
#pragma unroll
      for (int j = 0; j < 4; ++j) v[j] = u[j];
    }
  } else {
    u16x4 u = *(const u16x4*)(obA + (size_t)r * 256 + e0);
#pragma unroll
    for (int j = 0; j < 4; ++j) v[j] = bf2f(u[j]);
  }
  float s1 = v[0] + v[1] + v[2] + v[3];
  float s2 = v[0] * v[0] + v[1] * v[1] + v[2] * v[2] + v[3] * v[3];
#pragma unroll
  for (int o = 32; o > 0; o >>= 1) {
    s1 += __shfl_xor(s1, o, 64);
    s2 += __shfl_xor(s2, o, 64);
  }
  float mean = s1 * (1.f / 256.f);
  float var  = s2 * (1.f / 256.f) - mean * mean;
  float inv  = rsqrtf(var + 1e-5f);
  u16 o4[4];
#pragma unroll
  for (int j = 0; j < 4; ++j)
    o4[j] = f2bf((v[j] - mean) * inv * ldw(g, wo + e0 + j, isbf) + ldw(bta, wo + e0 + j, isbf));
  *(u16x4*)(xnb + (size_t)r * 256 + e0) = *(const u16x4*)o4;
}

// ---------------- 4-wave MFMA GEMM: 64x64 tile, BK=64, XCD-swizzled grid ----------
// T3-minimal glds pipeline: issue next tile's global_load_lds into buf[p^1]
// BEFORE the MFMA phase on buf[p]; the end-of-step barrier's vmcnt drain gives
// the DMA the whole MFMA phase to land. LDS dest wave-uniform + lane*16
// (fragment layout R2-verified). ONE barrier per K-step.
// OUTMODE 1: final dtype per flag. 2: bf16 [+res], optional echo to Out2.
// 3: cat buffer [+res]. 5: cols<512 -> softplus(v+bias)->bf16; cols 512-543 -> f32 Out2.
// RESMODE 0: none. 1: residual = x chain-mapped. 2: residual = bf16 resv.
template<int OUTMODE, int RESMODE>
__global__ __launch_bounds__(256) void gemm64(
    const u16* __restrict__ A, const u16* __restrict__ Wp, size_t woA, size_t woB, int mhalf,
    const void* __restrict__ resv, void* __restrict__ Out, void* __restrict__ Out2,
    const void* __restrict__ bias, size_t boA, size_t boB,
    const int* __restrict__ pf, int N, int K, int nbx)
{
  const int isbf = *pf;
  __shared__ __align__(16) u16 Asb[2][4096];
  __shared__ __align__(16) u16 Bsb[2][4096];
  int tid = threadIdx.x;
  int gidx = blockIdx.x;
  int xcd = gidx & 7, rest = gidx >> 3;
  int nIdx = rest % nbx, mGrp = rest / nbx;
  int n0 = nIdx * 64, m0 = (xcd + (mGrp << 3)) * 64;
  size_t wo = (mhalf && m0 >= mhalf) ? woB : woA;
  int w = tid >> 6, lane = tid & 63;
  int q = lane >> 4, r = lane & 15;
  const int wm0 = (w >> 1) * 2, wn0 = (w & 1) * 2;
  const int kbs = K >> 5;
  f32x4 acc[2][2];
#pragma unroll
  for (int i = 0; i < 2; ++i)
#pragma unroll
    for (int j = 0; j < 2; ++j) acc[i][j] = (f32x4){0.f, 0.f, 0.f, 0.f};

  // A: lane l of wave w fetches row m0+16w+(l&15), k-cols (l>>4)*8..+7 (16B);
  // lands at Asb + w*512 + l*8 = fragment order ((l>>4)*128 + (l&15)*8).
  const u16* asrc = A + (size_t)(m0 + (w << 4) + (lane & 15)) * K + ((lane >> 4) << 3);
  u16* albase = Asb[0] + w * 512;   // +4096 for buf 1
  // B: packed weight linear per 16-col block; wave w loads block (n0>>4)+w.
  const u16* bcol = Wp + wo + (size_t)((n0 >> 4) + w) * kbs * 512 + lane * 8;
  u16* blbase = Bsb[0] + w * 512;

  // prologue: stage K-tile 0 into buf 0
  glds16(asrc,      albase);
  glds16(asrc + 32, albase + 2048);
  glds16(bcol,       blbase);
  glds16(bcol + 512, blbase + 2048);
  __syncthreads();

  int p = 0;
  for (int k0 = 0; k0 < K; k0 += 64, p ^= 1) {
    if (k0 + 64 < K) {  // issue next tile's DMA; lands during MFMA phase
      int pn = p ^ 1;
      glds16(asrc + k0 + 64, albase + pn * 4096);
      glds16(asrc + k0 + 96, albase + pn * 4096 + 2048);
      const u16* bs = bcol + (size_t)((k0 + 64) >> 5) * 512;
      glds16(bs,       blbase + pn * 4096);
      glds16(bs + 512, blbase + pn * 4096 + 2048);
    }
#pragma unroll
    for (int ck = 0; ck < 2; ++ck) {
      const u16* Ab = Asb[p] + ck * 2048;
      const u16* Bb = Bsb[p] + ck * 2048;
      bf16x8 af[2], bfr[2];
#pragma unroll
      for (int i = 0; i < 2; ++i)
        af[i] = *(const bf16x8*)(Ab + ((wm0 + i) * 4 + q) * 128 + r * 8);
#pragma unroll
      for (int j = 0; j < 2; ++j)
        bfr[j] = *(const bf16x8*)(Bb + ((wn0 + j) * 4 + q) * 128 + r * 8);
#pragma unroll
      for (int i = 0; i < 2; ++i)
#pragma unroll
        for (int j = 0; j < 2; ++j)
          acc[i][j] = __builtin_amdgcn_mfma_f32_16x16x32_bf16(af[i], bfr[j], acc[i][j], 0, 0, 0);
    }
    __syncthreads();  // drains vmcnt: buf[p^1] complete; orders reads vs overwrite
  }
#pragma unroll
  for (int i = 0; i < 2; ++i) {
    int rowb = m0 + (wm0 + i) * 16 + q * 4;
#pragma unroll
    for (int j = 0; j < 2; ++j) {
      int col = n0 + (wn0 + j) * 16 + r;
#pragma unroll
      for (int t = 0; t < 4; ++t) {
        int row = rowb + t;
        float v = acc[i][j][t];
        if (OUTMODE == 2 || OUTMODE == 3) {
          if (RESMODE == 1) {
            int rr2 = row & 4095, ch = row >> 12;
            int bb = rr2 >> 11, ss = rr2 & 2047;
            int sr = ch ? (bb * S_LEN + (S_LEN - 1 - ss)) : rr2;
            v += ldw(resv, (size_t)sr * 256 + col, isbf);
          } else if (RESMODE == 2) {
            v += bf2f(((const u16*)resv)[(size_t)row * 256 + col]);
          }
        }
        if (OUTMODE == 1) {
          size_t lidx = (size_t)row * N + col;
          if (isbf) ((u16*)Out)[lidx] = f2bf(v); else ((float*)Out)[lidx] = v;
        } else if (OUTMODE == 2) {
          u16 ov = f2bf(v);
          ((u16*)Out)[(size_t)row * N + col] = ov;
          if (Out2) ((u16*)Out2)[(size_t)row * N + col] = ov;  // res_bf echo
        } else if (OUTMODE == 3) {
          int orow, cofx;
          if (row < 4096) { orow = row; cofx = 0; }
          else {
            int rr = row - 4096; int bb = rr >> 11, ss = rr & 2047;
            orow = bb * S_LEN + (S_LEN - 1 - ss); cofx = 256;
          }
          ((u16*)Out)[(size_t)orow * 512 + col + cofx] = f2bf(v);
        } else if (OUTMODE == 5) {
          if (col < 512) {
            float bv = ldw(bias, ((row < 4096) ? boA : boB) + col, isbf);
            ((u16*)Out)[(size_t)row * 512 + col] = f2bf(softplusf(v + bv));
          } else if (col < 544) {
            ((float*)Out2)[(size_t)row * 32 + (col - 512)] = v;
          }
        }
      }
    }
  }
}

// ---------------- causal depthwise conv K=4 + bias + SiLU, 8-wide vectorized ----
__global__ __launch_bounds__(256) void conv_kernel(
    const u16* __restrict__ xzb, const void* __restrict__ cw, const void* __restrict__ cb,
    int it, const int* __restrict__ pf, u16* __restrict__ xcb)
{
  const int isbf = *pf;
  int idx = blockIdx.x * 256 + threadIdx.x;  // 8192*64
  int r = idx >> 6, dg = idx & 63;
  int d0 = dg << 3;
  int chain = r >> 12, rr = r & 4095;
  int i = chain * 2 + it;
  size_t ow = (size_t)i * 2048, ob = (size_t)i * 512;
  int s = rr & 2047;
  float acc[8];
#pragma unroll
  for (int j = 0; j < 8; ++j) acc[j] = ldw(cb, ob + d0 + j, isbf);
#pragma unroll
  for (int k = 0; k < 4; ++k) {
    int t = s - 3 + k;
    if (t >= 0) {
      u16x8 xv = *(const u16x8*)(xzb + (((size_t)(r + t - s)) << 10) + d0);
#pragma unroll
      for (int j = 0; j < 8; ++j)
        acc[j] += ldw(cw, ow + (size_t)(d0 + j) * 4 + k, isbf) * bf2f(xv[j]);
    }
  }
  u16 outv[8];
#pragma unroll
  for (int j = 0; j < 8; ++j) outv[j] = f2bf(siluf(acc[j]));
  *(u16x8*)(xcb + ((size_t)r << 9) + d0) = *(const u16x8*)outv;
}

// ---------------- 3-phase scan: 4 n-states/thread; dBC is [rows][32] = B|C ----------
__global__ __launch_bounds__(256) void scan_p1_kernel(
    const u16* __restrict__ xcb, const u16* __restrict__ delb, const float* __restrict__ dBC,
    const float* __restrict__ Acp, int it, const int* __restrict__ pf,
    float* __restrict__ aggA, float* __restrict__ aggB)
{
  __shared__ float sb[32][16];   // B
  __shared__ u16 sdu[32][64];
  __shared__ u16 sxu[32][64];
  int tid = threadIdx.x;
  int di = tid >> 2, ng = tid & 3;
  int d0 = blockIdx.x << 6;
  int c = blockIdx.y, seq = blockIdx.z;
  int chain = seq >> 1, bb = seq & 1;
  int row0 = chain * 4096 + bb * S_LEN + c * CLEN;
  int i = chain * 2 + it;
  {
    int t = tid >> 3, e0 = (tid & 7) * 8;
    *(u16x8*)&sdu[t][e0] = *(const u16x8*)(delb + (size_t)(row0 + t) * 512 + d0 + e0);
    *(u16x8*)&sxu[t][e0] = *(const u16x8*)(xcb + (size_t)(row0 + t) * 512 + d0 + e0);
  }
  if (tid < 128) {
    int t = tid >> 2, e0 = (tid & 3) * 4;
    *(f32x4*)&sb[t][e0] = *(const f32x4*)(dBC + (size_t)(row0 + t) * 32 + e0);
  }
  f32x4 Ac = *(const f32x4*)(Acp + ((size_t)i * 512 + d0 + di) * 16 + ng * 4);
  __syncthreads();
  float h[4] = {0.f, 0.f, 0.f, 0.f};
  float ap[4] = {1.f, 1.f, 1.f, 1.f};
#pragma unroll 8
  for (int t = 0; t < CLEN; ++t) {
    float de = bf2f(sdu[t][di]);
    float dx = de * bf2f(sxu[t][di]);
    f32x4 B = *(const f32x4*)&sb[t][ng * 4];
#pragma unroll
    for (int j = 0; j < 4; ++j) {
      float e = __expf(de * Ac[j]);
      h[j] = e * h[j] + dx * B[j];
      ap[j] *= e;
    }
  }
  size_t o = (((size_t)(seq * NCHUNK + c) * DINNER) + d0 + di) * 16 + ng * 4;
  *(f32x4*)(aggA + o) = (f32x4){ap[0], ap[1], ap[2], ap[3]};
  *(f32x4*)(aggB + o) = (f32x4){h[0], h[1], h[2], h[3]};
}

// 512 x 64-thread blocks; chunk loads batched 8-deep (independent of recurrence).
__global__ __launch_bounds__(64) void scan_prefix_kernel(
    const float* __restrict__ aggA, float* __restrict__ aggB)
{
  int idx = blockIdx.x * 64 + threadIdx.x;   // 4*512*16
  int n = idx & 15, d = (idx >> 4) & 511, seq = idx >> 13;
  size_t o = (((size_t)(seq * NCHUNK) * DINNER) + d) * 16 + n;
  const size_t stride = (size_t)DINNER * 16;
  float h = 0.f;
  for (int c0 = 0; c0 < NCHUNK; c0 += 8) {
    float a[8], b[8];
#pragma unroll
    for (int j = 0; j < 8; ++j) {
      a[j] = aggA[o + (size_t)j * stride];
      b[j] = aggB[o + (size_t)j * stride];
    }
#pragma unroll
    for (int j = 0; j < 8; ++j) {
      aggB[o + (size_t)j * stride] = h;
      h = a[j] * h + b[j];
    }
    o += (size_t)8 * stride;
  }
}

__global__ __launch_bounds__(256) void scan_p3_kernel(
    const u16* __restrict__ xcb, const u16* __restrict__ delb, const float* __restrict__ dBC,
    const u16* __restrict__ xzb, const float* __restrict__ hpref,
    const float* __restrict__ Acp, const void* __restrict__ Dp,
    int it, const int* __restrict__ pf, u16* __restrict__ ymb)
{
  const int isbf = *pf;
  __shared__ float sbc[32][32];  // B | C
  __shared__ float sy[32][64];
  __shared__ u16 sdu[32][64];
  __shared__ u16 sxu[32][64];
  __shared__ u16 szu[32][64];
  int tid = threadIdx.x;
  int di = tid >> 2, ng = tid & 3;
  int d0 = blockIdx.x << 6;
  int c = blockIdx.y, seq = blockIdx.z;
  int chain = seq >> 1, bb = seq & 1;
  int row0 = chain * 4096 + bb * S_LEN + c * CLEN;
  int i = chain * 2 + it;
  size_t oD = (size_t)i * 512;
  {
    int t = tid >> 3, e0 = (tid & 7) * 8;
    *(u16x8*)&sdu[t][e0] = *(const u16x8*)(delb + (size_t)(row0 + t) * 512 + d0 + e0);
    *(u16x8*)&sxu[t][e0] = *(const u16x8*)(xcb + (size_t)(row0 + t) * 512 + d0 + e0);
    *(u16x8*)&szu[t][e0] = *(const u16x8*)(xzb + ((size_t)(row0 + t) << 10) + 512 + d0 + e0);
  }
  {
    int t = tid >> 3, e0 = (tid & 7) * 4;
    *(f32x4*)&sbc[t][e0] = *(const f32x4*)(dBC + (size_t)(row0 + t) * 32 + e0);
  }
  f32x4 Ac = *(const f32x4*)(Acp + ((size_t)i * 512 + d0 + di) * 16 + ng * 4);
  float Dv = ldw(Dp, oD + d0 + di, isbf);
  float h[4];
  size_t o = (((size_t)(seq * NCHUNK + c) * DINNER) + d0 + di) * 16 + ng * 4;
  {
    f32x4 v = *(const f32x4*)(hpref + o);
    h[0] = v[0]; h[1] = v[1]; h[2] = v[2]; h[3] = v[3];
  }
  __syncthreads();
#pragma unroll 8
  for (int t = 0; t < CLEN; ++t) {
    float de = bf2f(sdu[t][di]);
    float xv = bf2f(sxu[t][di]);
    float dx = de * xv;
    f32x4 B = *(const f32x4*)&sbc[t][ng * 4];
    f32x4 C = *(const f32x4*)&sbc[t][16 + ng * 4];
    float yc = 0.f;
#pragma unroll
    for (int j = 0; j < 4; ++j) {
      float e = __expf(de * Ac[j]);
      h[j] = e * h[j] + dx * B[j];
      yc += h[j] * C[j];
    }
    yc += __shfl_xor(yc, 1, 64);
    yc += __shfl_xor(yc, 2, 64);
    if (ng == 0) sy[t][di] = yc + Dv * xv;
  }
  __syncthreads();
  int dcol = tid & 63;
#pragma unroll
  for (int k = 0; k < 8; ++k) {
    int t = (tid >> 6) + k * 4;
    float y = sy[t][dcol];
    float z = bf2f(szu[t][dcol]);
    ymb[(size_t)(row0 + t) * 512 + d0 + dcol] = f2bf(y * siluf(z));
  }
}

extern "C" void kernel_launch(void* const* d_in, const int* in_sizes, int n_in,
                              void* d_out, int out_size, void* d_ws, size_t ws_size,
                              hipStream_t stream)
{
  const void* x       = d_in[0];
  const void* in_w    = d_in[1];
  const void* conv_w  = d_in[2];
  const void* conv_b  = d_in[3];
  const void* A_log   = d_in[4];
  const void* xd_w    = d_in[5];
  const void* xB_w    = d_in[6];
  const void* xC_w    = d_in[7];
  const void* dtp_w   = d_in[8];
  const void* dtp_b   = d_in[9];
  const void* Dp      = d_in[10];
  const void* out_w   = d_in[11];
  const void* ln_g    = d_in[12];
  const void* ln_b    = d_in[13];
  const void* merge_w = d_in[14];

  // ---- workspace (layout offsets unchanged from proven version) ----
  float* ws    = (float*)d_ws;
  u16*   res_bf= (u16*)ws;                       // 8192x256 u16 (region reserved 8MB)
  float* dBC   = ws + (size_t)8192 * 256;        // 8192x32 f32 (B|C)
  float* aggA  = dBC + (size_t)8192 * 32;        // 2M f32 (xn & ym alias)
  float* aggB  = aggA + (size_t)2097152;         // 2M f32 (-> hpref)
  u16*   xz_bf = (u16*)(aggB + (size_t)2097152); // 8192x1024 (obA alias head)
  u16*   xc_bf = xz_bf + (size_t)8192 * 1024;    // 8192x512
  u16*   del_bf= xc_bf + (size_t)8192 * 512;     // 8192x512 (cat alias head)
  u16*   Wp_in = del_bf + (size_t)8192 * 512;    // 4*256*1024
  u16*   Wp_out= Wp_in + (size_t)4 * 262144;     // 4*512*256
  u16*   Wp_mg = Wp_out + (size_t)4 * 131072;    // 512*256
  u16*   Wp_cmb= Wp_mg + (size_t)131072;         // 4*512*576
  float* Acp   = (float*)(Wp_cmb + (size_t)4 * 294912);  // 4*512*16 f32
  int*   flagp = (int*)(Acp + (size_t)4 * 8192);
  u16*   obA_bf= xz_bf;          // alias
  u16*   xn_bf = (u16*)aggA;     // alias
  u16*   ym_bf = (u16*)aggA;     // alias
  u16*   cat_bf= del_bf;         // alias

  dim3 blk(256);
  hipLaunchKernelGGL(prep_kernel, dim3(1536), blk, 0, stream,
      x, A_log, in_w, out_w, merge_w, xd_w, dtp_w, xB_w, xC_w, flagp,
      Acp, Wp_in, Wp_out, Wp_mg, Wp_cmb);

  for (int it = 0; it < 2; ++it) {
    hipLaunchKernelGGL(ln_kernel, dim3(2048), blk, 0, stream,
        x, obA_bf, it, ln_g, ln_b, flagp, xn_bf);
    hipLaunchKernelGGL((gemm64<2, 0>), dim3(16 * 128), blk, 0, stream,
        xn_bf, Wp_in, (size_t)it * 262144, (size_t)(2 + it) * 262144, 4096,
        (const void*)nullptr, (void*)xz_bf, (void*)nullptr,
        (const void*)nullptr, (size_t)0, (size_t)0, flagp, 1024, 256, 16);
    hipLaunchKernelGGL(conv_kernel, dim3(2048), blk, 0, stream,
        xz_bf, conv_w, conv_b, it, flagp, xc_bf);
    hipLaunchKernelGGL((gemm64<5, 0>), dim3(9 * 128), blk, 0, stream,
        xc_bf, Wp_cmb, (size_t)it * 294912, (size_t)(2 + it) * 294912, 4096,
        (const void*)nullptr, (void*)del_bf, (void*)dBC,
        dtp_b, (size_t)it * 512, (size_t)(2 + it) * 512, flagp, 576, 512, 9);
    hipLaunchKernelGGL(scan_p1_kernel, dim3(8, NCHUNK, 4), blk, 0, stream,
        xc_bf, del_bf, dBC, Acp, it, flagp, aggA, aggB);
    hipLaunchKernelGGL(scan_prefix_kernel, dim3(512), dim3(64), 0, stream, aggA, aggB);
    hipLaunchKernelGGL(scan_p3_kernel, dim3(8, NCHUNK, 4), blk, 0, stream,
        xc_bf, del_bf, dBC, xz_bf, aggB, Acp, Dp, it, flagp, ym_bf);
    if (it == 0) {
      // residual read directly from x (chain-mapped); echo output into res_bf
      hipLaunchKernelGGL((gemm64<2, 1>), dim3(4 * 128), blk, 0, stream,
          ym_bf, Wp_out, (size_t)0, (size_t)2 * 131072, 4096,
          x, (void*)obA_bf, (void*)res_bf,
          (const void*)nullptr, (size_t)0, (size_t)0, flagp, 256, 512, 4);
    } else {
      // residual = bf16 snapshot of obA (exact copy, taken by it=0's gemm-out)
      hipLaunchKernelGGL((gemm64<3, 2>), dim3(4 * 128), blk, 0, stream,
          ym_bf, Wp_out, (size_t)1 * 131072, (size_t)3 * 131072, 4096,
          (const void*)res_bf, (void*)cat_bf, (void*)nullptr,
          (const void*)nullptr, (size_t)0, (size_t)0, flagp, 256, 512, 4);
    }
  }
  hipLaunchKernelGGL((gemm64<1, 0>), dim3(4 * 64), blk, 0, stream,
      cat_bf, Wp_mg, (size_t)0, (size_t)0, 0,
      (const void*)nullptr, d_out, (void*)nullptr,
      (const void*)nullptr, (size_t)0, (size_t)0, flagp, 256, 512, 4);
}

// Round 9
// 392.192 us; speedup vs baseline: 1.0618x; 1.0618x over previous
//
#include <hip/hip_runtime.h>

#define S_LEN 2048
#define DINNER 512
#define NCHUNK 64
#define CLEN 32

typedef unsigned short u16;
typedef short bf16x8 __attribute__((ext_vector_type(8)));
typedef unsigned short u16x8 __attribute__((ext_vector_type(8)));  // 16 bytes
typedef unsigned short u16x4 __attribute__((ext_vector_type(4)));  // 8 bytes
typedef float f32x4 __attribute__((ext_vector_type(4)));

__device__ __forceinline__ float bf2f(u16 u) {
  unsigned int x = ((unsigned int)u) << 16;
  float f; __builtin_memcpy(&f, &x, 4); return f;
}
__device__ __forceinline__ u16 f2bf(float f) {
  unsigned int x; __builtin_memcpy(&x, &f, 4);
  return (u16)((x + 0x7FFFu + ((x >> 16) & 1u)) >> 16);
}
__device__ __forceinline__ float ldw(const void* p, size_t i, int isbf) {
  return isbf ? bf2f(((const u16*)p)[i]) : ((const float*)p)[i];
}
__device__ __forceinline__ float siluf(float x) { return x / (1.f + __expf(-x)); }
__device__ __forceinline__ float softplusf(float x) {
  if (x > 20.f) return x;
  return log1pf(__expf(x));
}

// ---------------- fused prologue: self-detect + apack + wpack + wpack_cmb ----------
// Each block detects input dtype itself (256 cached loads); block 0 publishes
// flagp for downstream kernels.
// Block ranges: [0,128) apack; [128,640) wpack in_w; [640,896) wpack out_w;
// [896,960) wpack merge_w; [960,1536) wpack_cmb.
// Packed W[K][N]: chunk c = nblk16*(K/32) + kblk32, 512 bf16 per chunk;
// inside: q*128 + (n&15)*8 + (k&7).
__global__ __launch_bounds__(256) void prep_kernel(
    const void* __restrict__ xinp,
    const void* __restrict__ A_log,
    const void* __restrict__ in_w, const void* __restrict__ out_w,
    const void* __restrict__ merge_w,
    const void* __restrict__ xdw, const void* __restrict__ dtpw,
    const void* __restrict__ xBw, const void* __restrict__ xCw,
    int* __restrict__ flagp,
    float* __restrict__ Acp, u16* __restrict__ Wp_in, u16* __restrict__ Wp_out,
    u16* __restrict__ Wp_mg, u16* __restrict__ Wp_cmb)
{
  int b = blockIdx.x;
  int tid = threadIdx.x;
  __shared__ int cnt_s;
  if (tid == 0) cnt_s = 0;
  __syncthreads();
  {
    u16 u = ((const u16*)xinp)[2 * tid];
    int e = (u >> 7) & 0xFF;
    if (e >= 0x60 && e <= 0x8F) atomicAdd(&cnt_s, 1);
  }
  __syncthreads();
  const int isbf = (cnt_s > 128) ? 1 : 0;
  if (b == 0 && tid == 0) *flagp = isbf;

  __shared__ float smem[32 * 163];  // tile[32][65] | xd[32][33] | wt[32][65]
  float* tile = smem;               // [k][n] -> tile[k*65+n]

  if (b < 128) {  // ---- apack: Acp = -exp(A_log), 32768 elems ----
    int idx = b * 256 + tid;
    Acp[idx] = -__expf(ldw(A_log, (size_t)idx, isbf));
    return;
  }
  b -= 128;

  if (b < 512 + 256 + 64) {  // ---- generic wpack ----
    const void* src; u16* dst; int K, N, nb64, kb, mat;
    if (b < 512)      { src = in_w;    dst = Wp_in;  K = 256; N = 1024;
                        nb64 = b % 16; kb = (b / 16) % 8; mat = b / 128; }
    else if (b < 768) { int c = b - 512; src = out_w; dst = Wp_out; K = 512; N = 256;
                        nb64 = c % 4; kb = (c / 4) % 16; mat = c / 64; }
    else              { int c = b - 768; src = merge_w; dst = Wp_mg; K = 512; N = 256;
                        nb64 = c % 4; kb = (c / 4) % 16; mat = 0; }
    size_t so = (size_t)mat * K * N;
    int kk = tid >> 3, nseg = (tid & 7) * 8;
#pragma unroll
    for (int j = 0; j < 8; ++j)
      tile[kk * 65 + nseg + j] =
          ldw(src, so + (size_t)(kb * 32 + kk) * N + nb64 * 64 + nseg + j, isbf);
    __syncthreads();
    int cc = tid >> 6, i0 = (tid & 63) * 8;
    int q = i0 >> 7, nn = (i0 >> 3) & 15;
    u16 outv[8];
#pragma unroll
    for (int j = 0; j < 8; ++j) outv[j] = f2bf(tile[(q * 8 + j) * 65 + cc * 16 + nn]);
    size_t doff = (size_t)mat * K * N + ((size_t)(nb64 * 4 + cc) * (K >> 5) + kb) * 512 + i0;
    *(u16x8*)(dst + doff) = *(const u16x8*)outv;
    return;
  }
  b -= 832;

  // ---- wpack_cmb: [512 x 576] = [ xd_w@dtp_w (512) | xB_w (16) | xC_w (16) | 0 ] ----
  {
    int nb64 = b % 9, kb = (b / 9) % 16, mat = b / 144;
    float* xd = smem + 32 * 65;       // [k][j] -> xd[k*33+j]
    float* wt = smem + 32 * 98;       // [j][n] -> wt[j*65+n]
    if (nb64 < 8) {
      {
        int k = tid >> 3, j0 = (tid & 7) * 4;
#pragma unroll
        for (int j = 0; j < 4; ++j)
          xd[k * 33 + j0 + j] =
              ldw(xdw, (size_t)mat * 16384 + (size_t)(kb * 32 + k) * 32 + j0 + j, isbf);
        int jj = tid >> 3, n0l = (tid & 7) * 8;
#pragma unroll
        for (int n = 0; n < 8; ++n)
          wt[jj * 65 + n0l + n] =
              ldw(dtpw, (size_t)mat * 16384 + (size_t)jj * 512 + nb64 * 64 + n0l + n, isbf);
      }
      __syncthreads();
      for (int l = tid; l < 2048; l += 256) {
        int k = l >> 6, n = l & 63;
        float a = 0.f;
#pragma unroll
        for (int j = 0; j < 32; ++j) a += xd[k * 33 + j] * wt[j * 65 + n];
        tile[k * 65 + n] = a;
      }
    } else {
      for (int l = tid; l < 2048; l += 256) {
        int k = l >> 6, n = l & 63;
        int kg = kb * 32 + k;
        float v = 0.f;
        if (n < 16)      v = ldw(xBw, (size_t)mat * 8192 + (size_t)kg * 16 + n, isbf);
        else if (n < 32) v = ldw(xCw, (size_t)mat * 8192 + (size_t)kg * 16 + (n - 16), isbf);
        tile[k * 65 + n] = v;
      }
    }
    __syncthreads();
    int cc = tid >> 6, i0 = (tid & 63) * 8;
    int q = i0 >> 7, nn = (i0 >> 3) & 15;
    u16 outv[8];
#pragma unroll
    for (int j = 0; j < 8; ++j) outv[j] = f2bf(tile[(q * 8 + j) * 65 + cc * 16 + nn]);
    size_t doff = (size_t)mat * 294912 + ((size_t)(nb64 * 4 + cc) * 16 + kb) * 512 + i0;
    *(u16x8*)(Wp_cmb + doff) = *(const u16x8*)outv;
  }
}

// ---------------- LayerNorm: wave-per-row, no LDS/barriers, x4 vectorized --------
__global__ __launch_bounds__(256) void ln_kernel(
    const void* __restrict__ x, const u16* __restrict__ obA, int it,
    const void* __restrict__ g, const void* __restrict__ bta,
    const int* __restrict__ pf, u16* __restrict__ xnb)
{
  const int isbf = *pf;
  int tid = threadIdx.x;
  int w = tid >> 6, lane = tid & 63;
  int r = blockIdx.x * 4 + w;
  int chain = r >> 12, rr = r & 4095;
  int i = chain * 2 + it;
  size_t wo = (size_t)i * 256;
  int e0 = lane * 4;
  float v[4];
  if (it == 0) {
    int b = rr >> 11, s = rr & 2047;
    int sr = chain ? (b * S_LEN + (S_LEN - 1 - s)) : rr;
    if (isbf) {
      u16x4 u = *(const u16x4*)((const u16*)x + (size_t)sr * 256 + e0);
#pragma unroll
      for (int j = 0; j < 4; ++j) v[j] = bf2f(u[j]);
    } else {
      f32x4 u = *(const f32x4*)((const float*)x + (size_t)sr * 256 + e0);
#pragma unroll
      for (int j = 0; j < 4; ++j) v[j] = u[j];
    }
  } else {
    u16x4 u = *(const u16x4*)(obA + (size_t)r * 256 + e0);
#pragma unroll
    for (int j = 0; j < 4; ++j) v[j] = bf2f(u[j]);
  }
  float s1 = v[0] + v[1] + v[2] + v[3];
  float s2 = v[0] * v[0] + v[1] * v[1] + v[2] * v[2] + v[3] * v[3];
#pragma unroll
  for (int o = 32; o > 0; o >>= 1) {
    s1 += __shfl_xor(s1, o, 64);
    s2 += __shfl_xor(s2, o, 64);
  }
  float mean = s1 * (1.f / 256.f);
  float var  = s2 * (1.f / 256.f) - mean * mean;
  float inv  = rsqrtf(var + 1e-5f);
  u16 o4[4];
#pragma unroll
  for (int j = 0; j < 4; ++j)
    o4[j] = f2bf((v[j] - mean) * inv * ldw(g, wo + e0 + j, isbf) + ldw(bta, wo + e0 + j, isbf));
  *(u16x4*)(xnb + (size_t)r * 256 + e0) = *(const u16x4*)o4;
}

// ---------------- 4-wave MFMA GEMM: 64x64 tile, BK=64, XCD-swizzled grid ----------
// Reg-staged, DEPTH-2 register prefetch (two named in-flight sets, manual
// unroll-by-2 so all register indices are static) + LDS double-buffer.
// Two barriers per 128-K (one per 64-K step, same rate as proven version).
// Consume-wait for a set sits a full K-step+barrier+MFMA after its issue.
// K must be a multiple of 128 (all call sites: 256/512).
// OUTMODE 1: final dtype per flag. 2: bf16 [+res], optional echo to Out2.
// 3: cat buffer [+res]. 5: cols<512 -> softplus(v+bias)->bf16; cols 512-543 -> f32 Out2.
// RESMODE 0: none. 1: residual = x chain-mapped. 2: residual = bf16 resv.
template<int OUTMODE, int RESMODE>
__global__ __launch_bounds__(256) void gemm64(
    const u16* __restrict__ A, const u16* __restrict__ Wp, size_t woA, size_t woB, int mhalf,
    const void* __restrict__ resv, void* __restrict__ Out, void* __restrict__ Out2,
    const void* __restrict__ bias, size_t boA, size_t boB,
    const int* __restrict__ pf, int N, int K, int nbx)
{
  const int isbf = *pf;
  __shared__ __align__(16) u16 Asb[2][4096];
  __shared__ __align__(16) u16 Bsb[2][4096];
  int tid = threadIdx.x;
  int gidx = blockIdx.x;
  int xcd = gidx & 7, rest = gidx >> 3;
  int nIdx = rest % nbx, mGrp = rest / nbx;
  int n0 = nIdx * 64, m0 = (xcd + (mGrp << 3)) * 64;
  size_t wo = (mhalf && m0 >= mhalf) ? woB : woA;
  int w = tid >> 6, lane = tid & 63;
  int q = lane >> 4, r = lane & 15;
  const int wm0 = (w >> 1) * 2, wn0 = (w & 1) * 2;
  const int kbs = K >> 5;
  f32x4 acc[2][2];
#pragma unroll
  for (int i = 0; i < 2; ++i)
#pragma unroll
    for (int j = 0; j < 2; ++j) acc[i][j] = (f32x4){0.f, 0.f, 0.f, 0.f};

  int sm = tid >> 2, sq = tid & 3;
  const u16* asrc = A + (size_t)(m0 + sm) * K + sq * 8;
  const int aoff = ((sm >> 4) * 4 + sq) * 128 + (sm & 15) * 8;
  int bnb = tid >> 6, binner = (tid & 63) * 8;
  const int boff = bnb * 512 + binner;
  const u16* bcol = Wp + wo + (size_t)((n0 >> 4) + bnb) * kbs * 512 + binner;

  // prologue: set A <- k-tile 0, set B <- k-tile 64
  u16x8 laA0 = *(const u16x8*)(asrc);
  u16x8 laA1 = *(const u16x8*)(asrc + 32);
  u16x8 lbA0 = *(const u16x8*)(bcol);
  u16x8 lbA1 = *(const u16x8*)(bcol + 512);
  u16x8 laB0 = *(const u16x8*)(asrc + 64);
  u16x8 laB1 = *(const u16x8*)(asrc + 96);
  u16x8 lbB0 = *(const u16x8*)(bcol + 1024);
  u16x8 lbB1 = *(const u16x8*)(bcol + 1536);

  for (int k0 = 0; k0 < K; k0 += 128) {
    // ---- half-step 0: buf0 <- set A; prefetch set A <- k0+128 ----
    *(u16x8*)(Asb[0] + aoff)        = laA0;
    *(u16x8*)(Asb[0] + aoff + 2048) = laA1;
    *(u16x8*)(Bsb[0] + boff)        = lbA0;
    *(u16x8*)(Bsb[0] + boff + 2048) = lbA1;
    __syncthreads();
    if (k0 + 128 < K) {
      laA0 = *(const u16x8*)(asrc + k0 + 128);
      laA1 = *(const u16x8*)(asrc + k0 + 160);
      const u16* bs = bcol + (size_t)((k0 + 128) >> 5) * 512;
      lbA0 = *(const u16x8*)bs;
      lbA1 = *(const u16x8*)(bs + 512);
    }
#pragma unroll
    for (int ck = 0; ck < 2; ++ck) {
      const u16* Ab = Asb[0] + ck * 2048;
      const u16* Bb = Bsb[0] + ck * 2048;
      bf16x8 af[2], bfr[2];
#pragma unroll
      for (int i = 0; i < 2; ++i)
        af[i] = *(const bf16x8*)(Ab + ((wm0 + i) * 4 + q) * 128 + r * 8);
#pragma unroll
      for (int j = 0; j < 2; ++j)
        bfr[j] = *(const bf16x8*)(Bb + ((wn0 + j) * 4 + q) * 128 + r * 8);
#pragma unroll
      for (int i = 0; i < 2; ++i)
#pragma unroll
        for (int j = 0; j < 2; ++j)
          acc[i][j] = __builtin_amdgcn_mfma_f32_16x16x32_bf16(af[i], bfr[j], acc[i][j], 0, 0, 0);
    }
    // ---- half-step 1: buf1 <- set B; prefetch set B <- k0+192 ----
    // (writes to buf1 race nothing: buf1's last reads completed before the
    //  barrier above; waves still in MFMA(buf0) touch only buf0)
    *(u16x8*)(Asb[1] + aoff)        = laB0;
    *(u16x8*)(Asb[1] + aoff + 2048) = laB1;
    *(u16x8*)(Bsb[1] + boff)        = lbB0;
    *(u16x8*)(Bsb[1] + boff + 2048) = lbB1;
    __syncthreads();
    if (k0 + 192 < K) {
      laB0 = *(const u16x8*)(asrc + k0 + 192);
      laB1 = *(const u16x8*)(asrc + k0 + 224);
      const u16* bs = bcol + (size_t)((k0 + 192) >> 5) * 512;
      lbB0 = *(const u16x8*)bs;
      lbB1 = *(const u16x8*)(bs + 512);
    }
#pragma unroll
    for (int ck = 0; ck < 2; ++ck) {
      const u16* Ab = Asb[1] + ck * 2048;
      const u16* Bb = Bsb[1] + ck * 2048;
      bf16x8 af[2], bfr[2];
#pragma unroll
      for (int i = 0; i < 2; ++i)
        af[i] = *(const bf16x8*)(Ab + ((wm0 + i) * 4 + q) * 128 + r * 8);
#pragma unroll
      for (int j = 0; j < 2; ++j)
        bfr[j] = *(const bf16x8*)(Bb + ((wn0 + j) * 4 + q) * 128 + r * 8);
#pragma unroll
      for (int i = 0; i < 2; ++i)
#pragma unroll
        for (int j = 0; j < 2; ++j)
          acc[i][j] = __builtin_amdgcn_mfma_f32_16x16x32_bf16(af[i], bfr[j], acc[i][j], 0, 0, 0);
    }
  }
#pragma unroll
  for (int i = 0; i < 2; ++i) {
    int rowb = m0 + (wm0 + i) * 16 + q * 4;
#pragma unroll
    for (int j = 0; j < 2; ++j) {
      int col = n0 + (wn0 + j) * 16 + r;
#pragma unroll
      for (int t = 0; t < 4; ++t) {
        int row = rowb + t;
        float v = acc[i][j][t];
        if (OUTMODE == 2 || OUTMODE == 3) {
          if (RESMODE == 1) {
            int rr2 = row & 4095, ch = row >> 12;
            int bb = rr2 >> 11, ss = rr2 & 2047;
            int sr = ch ? (bb * S_LEN + (S_LEN - 1 - ss)) : rr2;
            v += ldw(resv, (size_t)sr * 256 + col, isbf);
          } else if (RESMODE == 2) {
            v += bf2f(((const u16*)resv)[(size_t)row * 256 + col]);
          }
        }
        if (OUTMODE == 1) {
          size_t lidx = (size_t)row * N + col;
          if (isbf) ((u16*)Out)[lidx] = f2bf(v); else ((float*)Out)[lidx] = v;
        } else if (OUTMODE == 2) {
          u16 ov = f2bf(v);
          ((u16*)Out)[(size_t)row * N + col] = ov;
          if (Out2) ((u16*)Out2)[(size_t)row * N + col] = ov;  // res_bf echo
        } else if (OUTMODE == 3) {
          int orow, cofx;
          if (row < 4096) { orow = row; cofx = 0; }
          else {
            int rr = row - 4096; int bb = rr >> 11, ss = rr & 2047;
            orow = bb * S_LEN + (S_LEN - 1 - ss); cofx = 256;
          }
          ((u16*)Out)[(size_t)orow * 512 + col + cofx] = f2bf(v);
        } else if (OUTMODE == 5) {
          if (col < 512) {
            float bv = ldw(bias, ((row < 4096) ? boA : boB) + col, isbf);
            ((u16*)Out)[(size_t)row * 512 + col] = f2bf(softplusf(v + bv));
          } else if (col < 544) {
            ((float*)Out2)[(size_t)row * 32 + (col - 512)] = v;
          }
        }
      }
    }
  }
}

// ---------------- causal depthwise conv K=4 + bias + SiLU, 8-wide vectorized ----
__global__ __launch_bounds__(256) void conv_kernel(
    const u16* __restrict__ xzb, const void* __restrict__ cw, const void* __restrict__ cb,
    int it, const int* __restrict__ pf, u16* __restrict__ xcb)
{
  const int isbf = *pf;
  int idx = blockIdx.x * 256 + threadIdx.x;  // 8192*64
  int r = idx >> 6, dg = idx & 63;
  int d0 = dg << 3;
  int chain = r >> 12, rr = r & 4095;
  int i = chain * 2 + it;
  size_t ow = (size_t)i * 2048, ob = (size_t)i * 512;
  int s = rr & 2047;
  float acc[8];
#pragma unroll
  for (int j = 0; j < 8; ++j) acc[j] = ldw(cb, ob + d0 + j, isbf);
#pragma unroll
  for (int k = 0; k < 4; ++k) {
    int t = s - 3 + k;
    if (t >= 0) {
      u16x8 xv = *(const u16x8*)(xzb + (((size_t)(r + t - s)) << 10) + d0);
#pragma unroll
      for (int j = 0; j < 8; ++j)
        acc[j] += ldw(cw, ow + (size_t)(d0 + j) * 4 + k, isbf) * bf2f(xv[j]);
    }
  }
  u16 outv[8];
#pragma unroll
  for (int j = 0; j < 8; ++j) outv[j] = f2bf(siluf(acc[j]));
  *(u16x8*)(xcb + ((size_t)r << 9) + d0) = *(const u16x8*)outv;
}

// ---------------- 3-phase scan: 4 n-states/thread; dBC is [rows][32] = B|C ----------
__global__ __launch_bounds__(256) void scan_p1_kernel(
    const u16* __restrict__ xcb, const u16* __restrict__ delb, const float* __restrict__ dBC,
    const float* __restrict__ Acp, int it, const int* __restrict__ pf,
    float* __restrict__ aggA, float* __restrict__ aggB)
{
  __shared__ float sb[32][16];   // B
  __shared__ u16 sdu[32][64];
  __shared__ u16 sxu[32][64];
  int tid = threadIdx.x;
  int di = tid >> 2, ng = tid & 3;
  int d0 = blockIdx.x << 6;
  int c = blockIdx.y, seq = blockIdx.z;
  int chain = seq >> 1, bb = seq & 1;
  int row0 = chain * 4096 + bb * S_LEN + c * CLEN;
  int i = chain * 2 + it;
  {
    int t = tid >> 3, e0 = (tid & 7) * 8;
    *(u16x8*)&sdu[t][e0] = *(const u16x8*)(delb + (size_t)(row0 + t) * 512 + d0 + e0);
    *(u16x8*)&sxu[t][e0] = *(const u16x8*)(xcb + (size_t)(row0 + t) * 512 + d0 + e0);
  }
  if (tid < 128) {
    int t = tid >> 2, e0 = (tid & 3) * 4;
    *(f32x4*)&sb[t][e0] = *(const f32x4*)(dBC + (size_t)(row0 + t) * 32 + e0);
  }
  f32x4 Ac = *(const f32x4*)(Acp + ((size_t)i * 512 + d0 + di) * 16 + ng * 4);
  __syncthreads();
  float h[4] = {0.f, 0.f, 0.f, 0.f};
  float ap[4] = {1.f, 1.f, 1.f, 1.f};
#pragma unroll 8
  for (int t = 0; t < CLEN; ++t) {
    float de = bf2f(sdu[t][di]);
    float dx = de * bf2f(sxu[t][di]);
    f32x4 B = *(const f32x4*)&sb[t][ng * 4];
#pragma unroll
    for (int j = 0; j < 4; ++j) {
      float e = __expf(de * Ac[j]);
      h[j] = e * h[j] + dx * B[j];
      ap[j] *= e;
    }
  }
  size_t o = (((size_t)(seq * NCHUNK + c) * DINNER) + d0 + di) * 16 + ng * 4;
  *(f32x4*)(aggA + o) = (f32x4){ap[0], ap[1], ap[2], ap[3]};
  *(f32x4*)(aggB + o) = (f32x4){h[0], h[1], h[2], h[3]};
}

// 512 x 64-thread blocks; chunk loads batched 8-deep (independent of recurrence).
__global__ __launch_bounds__(64) void scan_prefix_kernel(
    const float* __restrict__ aggA, float* __restrict__ aggB)
{
  int idx = blockIdx.x * 64 + threadIdx.x;   // 4*512*16
  int n = idx & 15, d = (idx >> 4) & 511, seq = idx >> 13;
  size_t o = (((size_t)(seq * NCHUNK) * DINNER) + d) * 16 + n;
  const size_t stride = (size_t)DINNER * 16;
  float h = 0.f;
  for (int c0 = 0; c0 < NCHUNK; c0 += 8) {
    float a[8], b[8];
#pragma unroll
    for (int j = 0; j < 8; ++j) {
      a[j] = aggA[o + (size_t)j * stride];
      b[j] = aggB[o + (size_t)j * stride];
    }
#pragma unroll
    for (int j = 0; j < 8; ++j) {
      aggB[o + (size_t)j * stride] = h;
      h = a[j] * h + b[j];
    }
    o += (size_t)8 * stride;
  }
}

__global__ __launch_bounds__(256) void scan_p3_kernel(
    const u16* __restrict__ xcb, const u16* __restrict__ delb, const float* __restrict__ dBC,
    const u16* __restrict__ xzb, const float* __restrict__ hpref,
    const float* __restrict__ Acp, const void* __restrict__ Dp,
    int it, const int* __restrict__ pf, u16* __restrict__ ymb)
{
  const int isbf = *pf;
  __shared__ float sbc[32][32];  // B | C
  __shared__ float sy[32][64];
  __shared__ u16 sdu[32][64];
  __shared__ u16 sxu[32][64];
  __shared__ u16 szu[32][64];
  int tid = threadIdx.x;
  int di = tid >> 2, ng = tid & 3;
  int d0 = blockIdx.x << 6;
  int c = blockIdx.y, seq = blockIdx.z;
  int chain = seq >> 1, bb = seq & 1;
  int row0 = chain * 4096 + bb * S_LEN + c * CLEN;
  int i = chain * 2 + it;
  size_t oD = (size_t)i * 512;
  {
    int t = tid >> 3, e0 = (tid & 7) * 8;
    *(u16x8*)&sdu[t][e0] = *(const u16x8*)(delb + (size_t)(row0 + t) * 512 + d0 + e0);
    *(u16x8*)&sxu[t][e0] = *(const u16x8*)(xcb + (size_t)(row0 + t) * 512 + d0 + e0);
    *(u16x8*)&szu[t][e0] = *(const u16x8*)(xzb + ((size_t)(row0 + t) << 10) + 512 + d0 + e0);
  }
  {
    int t = tid >> 3, e0 = (tid & 7) * 4;
    *(f32x4*)&sbc[t][e0] = *(const f32x4*)(dBC + (size_t)(row0 + t) * 32 + e0);
  }
  f32x4 Ac = *(const f32x4*)(Acp + ((size_t)i * 512 + d0 + di) * 16 + ng * 4);
  float Dv = ldw(Dp, oD + d0 + di, isbf);
  float h[4];
  size_t o = (((size_t)(seq * NCHUNK + c) * DINNER) + d0 + di) * 16 + ng * 4;
  {
    f32x4 v = *(const f32x4*)(hpref + o);
    h[0] = v[0]; h[1] = v[1]; h[2] = v[2]; h[3] = v[3];
  }
  __syncthreads();
#pragma unroll 8
  for (int t = 0; t < CLEN; ++t) {
    float de = bf2f(sdu[t][di]);
    float xv = bf2f(sxu[t][di]);
    float dx = de * xv;
    f32x4 B = *(const f32x4*)&sbc[t][ng * 4];
    f32x4 C = *(const f32x4*)&sbc[t][16 + ng * 4];
    float yc = 0.f;
#pragma unroll
    for (int j = 0; j < 4; ++j) {
      float e = __expf(de * Ac[j]);
      h[j] = e * h[j] + dx * B[j];
      yc += h[j] * C[j];
    }
    yc += __shfl_xor(yc, 1, 64);
    yc += __shfl_xor(yc, 2, 64);
    if (ng == 0) sy[t][di] = yc + Dv * xv;
  }
  __syncthreads();
  int dcol = tid & 63;
#pragma unroll
  for (int k = 0; k < 8; ++k) {
    int t = (tid >> 6) + k * 4;
    float y = sy[t][dcol];
    float z = bf2f(szu[t][dcol]);
    ymb[(size_t)(row0 + t) * 512 + d0 + dcol] = f2bf(y * siluf(z));
  }
}

extern "C" void kernel_launch(void* const* d_in, const int* in_sizes, int n_in,
                              void* d_out, int out_size, void* d_ws, size_t ws_size,
                              hipStream_t stream)
{
  const void* x       = d_in[0];
  const void* in_w    = d_in[1];
  const void* conv_w  = d_in[2];
  const void* conv_b  = d_in[3];
  const void* A_log   = d_in[4];
  const void* xd_w    = d_in[5];
  const void* xB_w    = d_in[6];
  const void* xC_w    = d_in[7];
  const void* dtp_w   = d_in[8];
  const void* dtp_b   = d_in[9];
  const void* Dp      = d_in[10];
  const void* out_w   = d_in[11];
  const void* ln_g    = d_in[12];
  const void* ln_b    = d_in[13];
  const void* merge_w = d_in[14];

  // ---- workspace (layout offsets unchanged from proven version) ----
  float* ws    = (float*)d_ws;
  u16*   res_bf= (u16*)ws;                       // 8192x256 u16 (region reserved 8MB)
  float* dBC   = ws + (size_t)8192 * 256;        // 8192x32 f32 (B|C)
  float* aggA  = dBC + (size_t)8192 * 32;        // 2M f32 (xn & ym alias)
  float* aggB  = aggA + (size_t)2097152;         // 2M f32 (-> hpref)
  u16*   xz_bf = (u16*)(aggB + (size_t)2097152); // 8192x1024 (obA alias head)
  u16*   xc_bf = xz_bf + (size_t)8192 * 1024;    // 8192x512
  u16*   del_bf= xc_bf + (size_t)8192 * 512;     // 8192x512 (cat alias head)
  u16*   Wp_in = del_bf + (size_t)8192 * 512;    // 4*256*1024
  u16*   Wp_out= Wp_in + (size_t)4 * 262144;     // 4*512*256
  u16*   Wp_mg = Wp_out + (size_t)4 * 131072;    // 512*256
  u16*   Wp_cmb= Wp_mg + (size_t)131072;         // 4*512*576
  float* Acp   = (float*)(Wp_cmb + (size_t)4 * 294912);  // 4*512*16 f32
  int*   flagp = (int*)(Acp + (size_t)4 * 8192);
  u16*   obA_bf= xz_bf;          // alias
  u16*   xn_bf = (u16*)aggA;     // alias
  u16*   ym_bf = (u16*)aggA;     // alias
  u16*   cat_bf= del_bf;         // alias

  dim3 blk(256);
  hipLaunchKernelGGL(prep_kernel, dim3(1536), blk, 0, stream,
      x, A_log, in_w, out_w, merge_w, xd_w, dtp_w, xB_w, xC_w, flagp,
      Acp, Wp_in, Wp_out, Wp_mg, Wp_cmb);

  for (int it = 0; it < 2; ++it) {
    hipLaunchKernelGGL(ln_kernel, dim3(2048), blk, 0, stream,
        x, obA_bf, it, ln_g, ln_b, flagp, xn_bf);
    hipLaunchKernelGGL((gemm64<2, 0>), dim3(16 * 128), blk, 0, stream,
        xn_bf, Wp_in, (size_t)it * 262144, (size_t)(2 + it) * 262144, 4096,
        (const void*)nullptr, (void*)xz_bf, (void*)nullptr,
        (const void*)nullptr, (size_t)0, (size_t)0, flagp, 1024, 256, 16);
    hipLaunchKernelGGL(conv_kernel, dim3(2048), blk, 0, stream,
        xz_bf, conv_w, conv_b, it, flagp, xc_bf);
    hipLaunchKernelGGL((gemm64<5, 0>), dim3(9 * 128), blk, 0, stream,
        xc_bf, Wp_cmb, (size_t)it * 294912, (size_t)(2 + it) * 294912, 4096,
        (const void*)nullptr, (void*)del_bf, (void*)dBC,
        dtp_b, (size_t)it * 512, (size_t)(2 + it) * 512, flagp, 576, 512, 9);
    hipLaunchKernelGGL(scan_p1_kernel, dim3(8, NCHUNK, 4), blk, 0, stream,
        xc_bf, del_bf, dBC, Acp, it, flagp, aggA, aggB);
    hipLaunchKernelGGL(scan_prefix_kernel, dim3(512), dim3(64), 0, stream, aggA, aggB);
    hipLaunchKernelGGL(scan_p3_kernel, dim3(8, NCHUNK, 4), blk, 0, stream,
        xc_bf, del_bf, dBC, xz_bf, aggB, Acp, Dp, it, flagp, ym_bf);
    if (it == 0) {
      // residual read directly from x (chain-mapped); echo output into res_bf
      hipLaunchKernelGGL((gemm64<2, 1>), dim3(4 * 128), blk, 0, stream,
          ym_bf, Wp_out, (size_t)0, (size_t)2 * 131072, 4096,
          x, (void*)obA_bf, (void*)res_bf,
          (const void*)nullptr, (size_t)0, (size_t)0, flagp, 256, 512, 4);
    } else {
      // residual = bf16 snapshot of obA (exact copy, taken by it=0's gemm-out)
      hipLaunchKernelGGL((gemm64<3, 2>), dim3(4 * 128), blk, 0, stream,
          ym_bf, Wp_out, (size_t)1 * 131072, (size_t)3 * 131072, 4096,
          (const void*)res_bf, (void*)cat_bf, (void*)nullptr,
          (const void*)nullptr, (size_t)0, (size_t)0, flagp, 256, 512, 4);
    }
  }
  hipLaunchKernelGGL((gemm64<1, 0>), dim3(4 * 64), blk, 0, stream,
      cat_bf, Wp_mg, (size_t)0, (size_t)0, 0,
      (const void*)nullptr, d_out, (void*)nullptr,
      (const void*)nullptr, (size_t)0, (size_t)0, flagp, 256, 512, 4);
}